// Round 11
// baseline (1404.704 us; speedup 1.0000x reference)
//
#include <hip/hip_runtime.h>

#define B_ 4
#define C_ 384
#define N_ 4096
#define NH_ 8
#define D_ 48
#define PK_ 64
#define J3_ 1152
#define CN_ (C_*N_)

__device__ __forceinline__ float bf2f(unsigned short u){ return __uint_as_float(((unsigned)u)<<16); }
__device__ __forceinline__ unsigned short f2bf(float f){
  unsigned x = __float_as_uint(f);
  x += 0x7fffu + ((x>>16)&1u);
  return (unsigned short)(x>>16);
}

// ---- 1) qkv[b][n][j] = sum_c x[b][c][n] * Wq[c][src(j)], packed slices {q,k,v_sa}
// Scalar fp32, no LDS. x reads coalesced over n (lane = n), W reads warp-broadcast.
__global__ __launch_bounds__(256) void d_qkv(const float* __restrict__ x,
                                             const float* __restrict__ Wq,
                                             unsigned short* __restrict__ qkv){
  int b  = blockIdx.x;
  int n  = blockIdx.y*64 + (threadIdx.x & 63);
  int j0 = blockIdx.z*16 + (threadIdx.x>>6)*4;       // 4 consecutive packed cols
  int src = j0 + (j0 >= 768 ? 384 : 0);              // skip unused v_CA slice
  const float* xb = x  + (size_t)b*CN_ + n;
  const float* wb = Wq + src;
  float a0=0.f, a1=0.f, a2=0.f, a3=0.f;
  for(int c=0;c<C_;c++){
    float xv = xb[(size_t)c*N_];
    const float* w = wb + (size_t)c*1536;
    a0 = fmaf(xv, w[0], a0);
    a1 = fmaf(xv, w[1], a1);
    a2 = fmaf(xv, w[2], a2);
    a3 = fmaf(xv, w[3], a3);
  }
  unsigned short* q = qkv + ((size_t)(b*N_+n))*J3_ + j0;
  q[0]=f2bf(a0); q[1]=f2bf(a1); q[2]=f2bf(a2); q[3]=f2bf(a3);
}

// ---- 2) scale[b][c] = temp2[c/48] / max(||q[:,c]||, 1e-12) ; one block per (b,c)
__global__ __launch_bounds__(256) void d_norm(const unsigned short* __restrict__ qkv,
                                              const float* __restrict__ temp2,
                                              float* __restrict__ scale){
  __shared__ float red[256];
  int b = blockIdx.x, c = blockIdx.y;
  int t = threadIdx.x;
  float acc = 0.f;
  for(int n=t; n<N_; n+=256){
    float v = bf2f(qkv[((size_t)(b*N_+n))*J3_ + c]);
    acc = fmaf(v, v, acc);
  }
  red[t] = acc;
  __syncthreads();
  for(int s=128; s>0; s>>=1){
    if(t < s) red[t] += red[t+s];
    __syncthreads();
  }
  if(t == 0) scale[b*C_ + c] = temp2[c/D_] / fmaxf(sqrtf(red[0]), 1e-12f);
}

// ---- 3) kv[bs][c][kk] = sum_n qkv[b][n][(s+1)*384+c] * EF[n][kk]
// One thread per output. qkv read is warp-broadcast, EF coalesced.
__global__ __launch_bounds__(256) void d_kvproj(const unsigned short* __restrict__ qkv,
                                                const float* __restrict__ EF,
                                                float* __restrict__ kv){
  int bs = blockIdx.x;                       // b*2+s
  int b = bs>>1, s = bs&1;
  int c  = blockIdx.y*4 + (threadIdx.x>>6);
  int kk = threadIdx.x & 63;
  const unsigned short* base = qkv + (size_t)b*N_*J3_ + (s+1)*384 + c;
  float acc = 0.f;
  for(int n=0;n<N_;n++)
    acc = fmaf(bf2f(base[(size_t)n*J3_]), EF[(size_t)n*PK_ + kk], acc);
  kv[((size_t)(bs*C_) + c)*PK_ + kk] = acc;
}

// ---- 4) attention: one thread per (b,h,n); all math lane-local fp32.
// xsa flat layout (d*8+h)*N + n (faithful reshape), coalesced over n.
__global__ __launch_bounds__(256) void d_attn(const unsigned short* __restrict__ qkv,
                                              const float* __restrict__ scale,
                                              const float* __restrict__ kv,
                                              float* __restrict__ xsa){
  int b = blockIdx.x, h = blockIdx.y;
  int n = blockIdx.z*256 + threadIdx.x;
  const unsigned short* qrow = qkv + ((size_t)(b*N_+n))*J3_ + h*D_;
  const float* scl = scale + b*C_ + h*D_;
  float q[D_];
  #pragma unroll
  for(int d=0; d<D_; d++) q[d] = bf2f(qrow[d]) * scl[d];
  const float* kp = kv + ((size_t)((b*2+0)*C_) + h*D_)*PK_;
  const float* vp = kv + ((size_t)((b*2+1)*C_) + h*D_)*PK_;
  float lg[PK_];
  float mx = -1e30f;
  #pragma unroll
  for(int kk=0; kk<PK_; kk++){
    float acc = 0.f;
    #pragma unroll
    for(int d=0; d<D_; d++) acc = fmaf(q[d], kp[(size_t)d*PK_ + kk], acc);
    lg[kk] = acc;
    mx = fmaxf(mx, acc);
  }
  float ssum = 0.f;
  #pragma unroll
  for(int kk=0; kk<PK_; kk++){ lg[kk] = __expf(lg[kk] - mx); ssum += lg[kk]; }
  float inv = 1.f / ssum;
  float* xo = xsa + (size_t)b*CN_ + (size_t)h*N_ + n;
  #pragma unroll
  for(int d=0; d<D_; d++){
    float acc = 0.f;
    #pragma unroll
    for(int kk=0; kk<PK_; kk++) acc = fmaf(lg[kk], vp[(size_t)d*PK_ + kk], acc);
    xo[(size_t)(d*8)*N_] = acc * inv;     // flat (d*8+h)*N + n
  }
}

// ---- 5) out[b][c][n] = xsa[b][n*384+c] (faithful reshape), tiled transpose ----
__global__ __launch_bounds__(256) void k_tout(const float* __restrict__ xsa, float* __restrict__ out){
  __shared__ float tile[32][33];
  int b = blockIdx.z, n0 = blockIdx.x*32, c0 = blockIdx.y*32;
  int t = threadIdx.x, tr = t>>5, tc = t&31;
  #pragma unroll
  for(int i=0;i<4;i++)
    tile[tr+i*8][tc] = xsa[(size_t)b*CN_ + (size_t)(n0+tr+i*8)*C_ + c0+tc];
  __syncthreads();
  #pragma unroll
  for(int i=0;i<4;i++)
    out[(size_t)b*CN_ + (size_t)(c0+tr+i*8)*N_ + n0+tc] = tile[tc][tr+i*8];
}

extern "C" void kernel_launch(void* const* d_in, const int* in_sizes, int n_in,
                              void* d_out, int out_size, void* d_ws, size_t ws_size,
                              hipStream_t stream){
  const float* x     = (const float*)d_in[0];
  const float* Wq    = (const float*)d_in[1];
  const float* EF    = (const float*)d_in[2];
  const float* temp2 = (const float*)d_in[3];
  float* out = (float*)d_out;
  char* ws = (char*)d_ws;
  // Compact ws layout, total 63,707,136 bytes (< 64 MB). No aliasing.
  unsigned short* qkv = (unsigned short*)(ws);             // 37,748,736
  float* xsa          = (float*)(ws + 37748736);           // 25,165,824 (ends 62,914,560)
  float* scale        = (float*)(ws + 62914560);           //      6,144
  float* kv           = (float*)(ws + 62920704);           //    786,432 (ends 63,707,136)

  d_qkv   <<<dim3(4,64,72), 256, 0, stream>>>(x, Wq, qkv);
  d_norm  <<<dim3(4,384),   256, 0, stream>>>(qkv, temp2, scale);
  d_kvproj<<<dim3(8,96),    256, 0, stream>>>(qkv, EF, kv);
  d_attn  <<<dim3(4,8,16),  256, 0, stream>>>(qkv, scale, kv, xsa);
  k_tout  <<<dim3(128,12,4),256, 0, stream>>>(xsa, out);
}